// Round 2
// baseline (97.690 us; speedup 1.0000x reference)
//
#include <hip/hip_runtime.h>
#include <hip/hip_bf16.h>

// out[b, :] = (1/K) * sum_k embed[ids[b,k], :]
// B=8192, K=32, D=128, V=100000.
//
// R2 mapping: ONE wave64 per output row.
//   lane = c + 32*parity, c in [0,32) = float4 chunk of D, parity in {0,1}.
//   Lane sums neighbors k = 2*j + parity, j in [0,16)  (16 loads in flight,
//   ~64 VGPRs of load destinations instead of 128 -> full occupancy).
//   Final: 4x shfl_xor(32) folds the two k-parities together.
// Block = 256 threads = 4 rows. Grid = 2048 blocks = 8 blocks/CU -> 32 waves/CU.

#define K_NEIGH 32
#define D4      32   // D/4 float4 chunks per row
#define ROWS_PER_BLOCK 4

__global__ __launch_bounds__(256, 8) void mean_agg_kernel(
    const int* __restrict__ ids,        // [B, K] int32
    const float4* __restrict__ embed,   // [V, D/4] float4
    float4* __restrict__ out)           // [B, D/4] float4
{
    const int tid    = threadIdx.x;
    const int row    = blockIdx.x * ROWS_PER_BLOCK + (tid >> 6);
    const int lane   = tid & 63;
    const int c      = lane & 31;
    const int parity = lane >> 5;

    // Coalesced id load: lane holds ids[row, c] (both halves load the same
    // 128B line -> one transaction each, L1-hit for the second).
    const int my_id = ids[row * K_NEIGH + c];

    float4 acc = make_float4(0.f, 0.f, 0.f, 0.f);

#pragma unroll
    for (int j = 0; j < K_NEIGH / 2; ++j) {
        const int k  = 2 * j + parity;
        const int id = __shfl(my_id, k, 64);   // per-lane src: 2j or 2j+1
        const float4 v = embed[(long)id * D4 + c];
        acc.x += v.x; acc.y += v.y; acc.z += v.z; acc.w += v.w;
    }

    // Fold the two k-parities (lane ^ 32 holds the other half's partial sum).
    acc.x += __shfl_xor(acc.x, 32, 64);
    acc.y += __shfl_xor(acc.y, 32, 64);
    acc.z += __shfl_xor(acc.z, 32, 64);
    acc.w += __shfl_xor(acc.w, 32, 64);

    if (parity == 0) {
        const float s = 1.0f / (float)K_NEIGH;
        acc.x *= s; acc.y *= s; acc.z *= s; acc.w *= s;
        out[row * D4 + c] = acc;
    }
}

extern "C" void kernel_launch(void* const* d_in, const int* in_sizes, int n_in,
                              void* d_out, int out_size, void* d_ws, size_t ws_size,
                              hipStream_t stream) {
    const int*    ids   = (const int*)d_in[0];      // [B, K] int32
    const float4* embed = (const float4*)d_in[1];   // [V, D/4]
    float4*       out   = (float4*)d_out;           // [B, D/4]

    const int B = 8192;
    dim3 grid(B / ROWS_PER_BLOCK);
    dim3 block(256);
    mean_agg_kernel<<<grid, block, 0, stream>>>(ids, embed, out);
}

// Round 3
// 96.042 us; speedup vs baseline: 1.0172x; 1.0172x over previous
//
#include <hip/hip_runtime.h>
#include <hip/hip_bf16.h>

// out[b, :] = (1/K) * sum_k embed[ids[b,k], :]
// B=8192, K=32, D=128, V=100000.
//
// R3: latency-bound fix — maximize loads in flight per wave.
//   One wave64 per row. lane = float2 chunk of D (D/2 = 64 chunks -> 512B/row
//   per wave-load, fully coalesced). k is WAVE-UNIFORM: row is forced scalar
//   (readfirstlane), the 32 ids load as scalar s_load into SGPRs, and each
//   gather is global_load_dwordx2 with SGPR base + lane*8 offset — no shfl,
//   no lgkm dependency, ~1 VGPR of address cost for all loads.
//   Loads issue in 2 batches of 16 (v[16] filled before any accumulate):
//   16 x 512B = 8KB in flight per wave; 16 waves/CU via launch_bounds(256,4).

#define K_NEIGH 32
#define D2      64   // D/2 float2 chunks per row
#define ROWS_PER_BLOCK 4
#define BATCH 16

__global__ __launch_bounds__(256, 4) void mean_agg_kernel(
    const int* __restrict__ ids,        // [B, K] int32
    const float2* __restrict__ embed,   // [V, D/2] float2
    float2* __restrict__ out)           // [B, D/2] float2
{
    const int lane = threadIdx.x & 63;
    int row = blockIdx.x * ROWS_PER_BLOCK + (threadIdx.x >> 6);
    row = __builtin_amdgcn_readfirstlane(row);   // force wave-uniform -> SGPR

    // Wave-uniform id fetch: compiler should emit s_load_dwordx8/x16.
    const int* __restrict__ rowids = ids + row * K_NEIGH;
    int sid[K_NEIGH];
#pragma unroll
    for (int k = 0; k < K_NEIGH; ++k) sid[k] = rowids[k];

    float2 acc = make_float2(0.f, 0.f);

#pragma unroll
    for (int half = 0; half < K_NEIGH / BATCH; ++half) {
        float2 v[BATCH];
        // Phase 1: issue all 16 gathers (independent, SGPR-base addressing).
#pragma unroll
        for (int j = 0; j < BATCH; ++j) {
            const int id = sid[half * BATCH + j];
            v[j] = embed[(long)id * D2 + lane];
        }
        // Phase 2: drain + accumulate (compiler staggers vmcnt waits).
#pragma unroll
        for (int j = 0; j < BATCH; ++j) {
            acc.x += v[j].x;
            acc.y += v[j].y;
        }
    }

    const float s = 1.0f / (float)K_NEIGH;
    out[row * D2 + lane] = make_float2(acc.x * s, acc.y * s);
}

extern "C" void kernel_launch(void* const* d_in, const int* in_sizes, int n_in,
                              void* d_out, int out_size, void* d_ws, size_t ws_size,
                              hipStream_t stream) {
    const int*    ids   = (const int*)d_in[0];      // [B, K] int32
    const float2* embed = (const float2*)d_in[1];   // [V, D/2]
    float2*       out   = (float2*)d_out;           // [B, D/2]

    const int B = 8192;
    dim3 grid(B / ROWS_PER_BLOCK);
    dim3 block(256);
    mean_agg_kernel<<<grid, block, 0, stream>>>(ids, embed, out);
}